// Round 1
// baseline (762.309 us; speedup 1.0000x reference)
//
#include <hip/hip_runtime.h>
#include <math.h>

#define IN_C 128
#define OUT_C 64
#define ALPHA 0.2f

// ---------------------------------------------------------------------------
// Kernel 1: h = x @ W, s = h . a1, t = h . a2
// One wave (64 lanes) per node; lane c computes h[node][c].
// W (128x64 = 32KB) staged in LDS; x row read via broadcast loads.
// ---------------------------------------------------------------------------
__global__ __launch_bounds__(256) void gemm_st_kernel(
    const float* __restrict__ x, const float* __restrict__ W,
    const float* __restrict__ a, float* __restrict__ h,
    float* __restrict__ s, float* __restrict__ t, int n_nodes) {
  __shared__ float Ws[IN_C * OUT_C];
  for (int i = threadIdx.x; i < IN_C * OUT_C; i += blockDim.x) Ws[i] = W[i];
  __syncthreads();

  const int wave = threadIdx.x >> 6;
  const int lane = threadIdx.x & 63;
  const int waves_total = gridDim.x * (blockDim.x >> 6);

  for (int node = blockIdx.x * (blockDim.x >> 6) + wave; node < n_nodes;
       node += waves_total) {
    const float* xr = x + (size_t)node * IN_C;
    float acc = 0.f;
#pragma unroll 8
    for (int k = 0; k < IN_C; ++k) {
      acc += xr[k] * Ws[k * OUT_C + lane];  // bank = lane%32: 2-way, free
    }
    h[(size_t)node * OUT_C + lane] = acc;

    float sv = acc * a[lane];
    float tv = acc * a[OUT_C + lane];
#pragma unroll
    for (int off = 32; off; off >>= 1) {
      sv += __shfl_down(sv, off, 64);
      tv += __shfl_down(tv, off, 64);
    }
    if (lane == 0) {
      s[node] = sv;
      t[node] = tv;
    }
  }
}

// ---------------------------------------------------------------------------
// Kernel 2: edge scatter. One wave per edge; lane c handles channel c.
// w = exp(leaky_relu(s[u] + t[v])); out[u][c] += w * h[v][c]; expsum[u] += w
// ---------------------------------------------------------------------------
__global__ __launch_bounds__(256) void edge_kernel(
    const int* __restrict__ src, const int* __restrict__ dst,
    const float* __restrict__ h, const float* __restrict__ s,
    const float* __restrict__ t, float* __restrict__ out,
    float* __restrict__ expsum, int E) {
  const int lane = threadIdx.x & 63;
  const int wave_id = (blockIdx.x * blockDim.x + threadIdx.x) >> 6;
  const int waves_total = (gridDim.x * blockDim.x) >> 6;

  for (int e = wave_id; e < E; e += waves_total) {
    const int u = src[e];
    const int v = dst[e];
    const float z = s[u] + t[v];
    const float w = expf(z > 0.f ? z : ALPHA * z);
    const float hv = h[(size_t)v * OUT_C + lane];
    atomicAdd(&out[(size_t)u * OUT_C + lane], w * hv);
    if (lane == 0) atomicAdd(&expsum[u], w);
  }
}

// ---------------------------------------------------------------------------
// Kernel 3: add self-loop contribution (exclusive per node -> no atomics
// needed) and divide by the expsum. One thread per (node, channel).
// ---------------------------------------------------------------------------
__global__ __launch_bounds__(256) void finalize_kernel(
    const float* __restrict__ h, const float* __restrict__ s,
    const float* __restrict__ t, const float* __restrict__ expsum,
    float* __restrict__ out, int n_nodes) {
  const int idx = blockIdx.x * blockDim.x + threadIdx.x;
  if (idx >= n_nodes * OUT_C) return;
  const int node = idx >> 6;  // OUT_C == 64
  const float z = s[node] + t[node];
  const float w = expf(z > 0.f ? z : ALPHA * z);
  out[idx] = (out[idx] + w * h[idx]) / (expsum[node] + w);
}

extern "C" void kernel_launch(void* const* d_in, const int* in_sizes, int n_in,
                              void* d_out, int out_size, void* d_ws,
                              size_t ws_size, hipStream_t stream) {
  const float* x = (const float*)d_in[0];
  const float* W = (const float*)d_in[1];
  const float* a = (const float*)d_in[2];
  const int* edge_index = (const int*)d_in[3];

  const int n_nodes = in_sizes[0] / IN_C;
  const int E = in_sizes[3] / 2;
  const int* src = edge_index;
  const int* dst = edge_index + E;

  float* out = (float*)d_out;

  // Workspace layout
  float* h = (float*)d_ws;                    // n_nodes * 64
  float* s = h + (size_t)n_nodes * OUT_C;     // n_nodes
  float* t = s + n_nodes;                     // n_nodes
  float* expsum = t + n_nodes;                // n_nodes

  // Zero the accumulators (d_out / d_ws are poisoned with 0xAA each call).
  hipMemsetAsync(out, 0, (size_t)n_nodes * OUT_C * sizeof(float), stream);
  hipMemsetAsync(expsum, 0, (size_t)n_nodes * sizeof(float), stream);

  // Kernel 1: h, s, t
  {
    const int waves_per_block = 4;  // 256 threads
    const int grid = (n_nodes + waves_per_block - 1) / waves_per_block;
    gemm_st_kernel<<<grid, 256, 0, stream>>>(x, W, a, h, s, t, n_nodes);
  }

  // Kernel 2: edge scatter (one wave per edge)
  {
    const int edges_per_block = 4;  // 4 waves of 64
    const int grid = (E + edges_per_block - 1) / edges_per_block;
    edge_kernel<<<grid, 256, 0, stream>>>(src, dst, h, s, t, out, expsum, E);
  }

  // Kernel 3: self-loop + normalize
  {
    const int total = n_nodes * OUT_C;
    const int grid = (total + 255) / 256;
    finalize_kernel<<<grid, 256, 0, stream>>>(h, s, t, expsum, out, n_nodes);
  }
}

// Round 2
// 740.355 us; speedup vs baseline: 1.0297x; 1.0297x over previous
//
#include <hip/hip_runtime.h>
#include <math.h>

#define IN_C 128
#define OUT_C 64
#define ALPHA 0.2f

// ---------------------------------------------------------------------------
// Kernel 1: h = x @ W, s = h . a1, t = h . a2
// One wave per 2 nodes; lane c computes h[node][c]. W staged in LDS
// (bank = lane%32 -> 2-way aliasing, free on gfx950).
// ---------------------------------------------------------------------------
__global__ __launch_bounds__(256) void gemm_st_kernel(
    const float* __restrict__ x, const float* __restrict__ W,
    const float* __restrict__ a, float* __restrict__ h,
    float* __restrict__ s, float* __restrict__ t, int n_nodes) {
  __shared__ float Ws[IN_C * OUT_C];
  for (int i = threadIdx.x; i < IN_C * OUT_C; i += blockDim.x) Ws[i] = W[i];
  __syncthreads();

  const int wave = threadIdx.x >> 6;
  const int lane = threadIdx.x & 63;
  const int waves_total = gridDim.x * (blockDim.x >> 6);
  const int gwave = blockIdx.x * (blockDim.x >> 6) + wave;

  for (int base = gwave * 2; base < n_nodes; base += waves_total * 2) {
    const int n0 = base;
    const int n1 = base + 1;
    const bool has1 = (n1 < n_nodes);
    const float* x0 = x + (size_t)n0 * IN_C;
    const float* x1 = x + (size_t)(has1 ? n1 : n0) * IN_C;
    float acc0 = 0.f, acc1 = 0.f;
#pragma unroll 8
    for (int k = 0; k < IN_C; ++k) {
      const float wv = Ws[k * OUT_C + lane];
      acc0 += x0[k] * wv;
      acc1 += x1[k] * wv;
    }
    h[(size_t)n0 * OUT_C + lane] = acc0;
    if (has1) h[(size_t)n1 * OUT_C + lane] = acc1;

    const float a1v = a[lane];
    const float a2v = a[OUT_C + lane];
    float sv0 = acc0 * a1v, tv0 = acc0 * a2v;
    float sv1 = acc1 * a1v, tv1 = acc1 * a2v;
#pragma unroll
    for (int off = 32; off; off >>= 1) {
      sv0 += __shfl_down(sv0, off, 64);
      tv0 += __shfl_down(tv0, off, 64);
      sv1 += __shfl_down(sv1, off, 64);
      tv1 += __shfl_down(tv1, off, 64);
    }
    if (lane == 0) {
      s[n0] = sv0;
      t[n0] = tv0;
      if (has1) {
        s[n1] = sv1;
        t[n1] = tv1;
      }
    }
  }
}

// ---------------------------------------------------------------------------
// CSR build: degree histogram -> exclusive scan -> cursor scatter
// ---------------------------------------------------------------------------
__global__ __launch_bounds__(256) void hist_kernel(const int* __restrict__ src,
                                                   int* __restrict__ cnt,
                                                   int E) {
  const int e = blockIdx.x * blockDim.x + threadIdx.x;
  if (e < E) atomicAdd(&cnt[src[e]], 1);
}

// Single 1024-thread block scans N counts into exclusive offsets + cursor.
__global__ __launch_bounds__(1024) void scan_kernel(const int* __restrict__ cnt,
                                                    int* __restrict__ offs,
                                                    int* __restrict__ cursor,
                                                    int n) {
  __shared__ int sums[1024];
  const int tid = threadIdx.x;
  const int chunk = (n + 1023) >> 10;
  const int start = tid * chunk;
  const int end = min(start + chunk, n);
  int sum = 0;
  for (int i = start; i < end; ++i) sum += cnt[i];
  sums[tid] = sum;
  __syncthreads();
  int val = sum;
  for (int off = 1; off < 1024; off <<= 1) {
    int other = (tid >= off) ? sums[tid - off] : 0;
    __syncthreads();
    val += other;
    sums[tid] = val;
    __syncthreads();
  }
  int prefix = val - sum;  // exclusive prefix of this thread's chunk
  for (int i = start; i < end; ++i) {
    const int c = cnt[i];
    offs[i] = prefix;
    cursor[i] = prefix;
    prefix += c;
  }
  if (tid == 1023) offs[n] = prefix;
}

__global__ __launch_bounds__(256) void scatter_kernel(
    const int* __restrict__ src, const int* __restrict__ dst,
    int* __restrict__ cursor, int* __restrict__ dst_sorted, int E) {
  const int e = blockIdx.x * blockDim.x + threadIdx.x;
  if (e < E) {
    const int pos = atomicAdd(&cursor[src[e]], 1);
    dst_sorted[pos] = dst[e];
  }
}

// ---------------------------------------------------------------------------
// Aggregate: one wave per node, lane = channel. Gathers neighbor rows,
// accumulates numerator in registers, denom redundantly in all lanes,
// folds in self-loop, single store. No atomics anywhere.
// ---------------------------------------------------------------------------
__global__ __launch_bounds__(256) void aggregate_kernel(
    const int* __restrict__ offs, const int* __restrict__ dst_sorted,
    const float* __restrict__ h, const float* __restrict__ s,
    const float* __restrict__ t, float* __restrict__ out, int n_nodes) {
  const int lane = threadIdx.x & 63;
  const int gwave = (blockIdx.x * blockDim.x + threadIdx.x) >> 6;
  const int waves_total = (gridDim.x * blockDim.x) >> 6;

  for (int u = gwave; u < n_nodes; u += waves_total) {
    const float su = s[u];
    const int beg = offs[u];
    const int end = offs[u + 1];

    // self-loop
    const float z0 = su + t[u];
    const float w0 = expf(z0 > 0.f ? z0 : ALPHA * z0);
    float acc = w0 * h[(size_t)u * OUT_C + lane];
    float denom = w0;

#pragma unroll 4
    for (int j = beg; j < end; ++j) {
      const int v = dst_sorted[j];
      const float z = su + t[v];
      const float w = expf(z > 0.f ? z : ALPHA * z);
      acc += w * h[(size_t)v * OUT_C + lane];
      denom += w;
    }
    out[(size_t)u * OUT_C + lane] = acc / denom;
  }
}

extern "C" void kernel_launch(void* const* d_in, const int* in_sizes, int n_in,
                              void* d_out, int out_size, void* d_ws,
                              size_t ws_size, hipStream_t stream) {
  const float* x = (const float*)d_in[0];
  const float* W = (const float*)d_in[1];
  const float* a = (const float*)d_in[2];
  const int* edge_index = (const int*)d_in[3];

  const int n_nodes = in_sizes[0] / IN_C;
  const int E = in_sizes[3] / 2;
  const int* src = edge_index;
  const int* dst = edge_index + E;

  float* out = (float*)d_out;

  // Workspace layout (floats/ints are both 4B):
  float* h = (float*)d_ws;                        // n_nodes*64
  float* s = h + (size_t)n_nodes * OUT_C;         // n_nodes
  float* t = s + n_nodes;                         // n_nodes
  int* cnt = (int*)(t + n_nodes);                 // n_nodes
  int* offs = cnt + n_nodes;                      // n_nodes+1
  int* cursor = offs + n_nodes + 1;               // n_nodes
  int* dst_sorted = cursor + n_nodes;             // E

  hipMemsetAsync(cnt, 0, (size_t)n_nodes * sizeof(int), stream);

  // h, s, t (independent of CSR build)
  {
    const int waves_per_block = 4;
    const int nodes_per_block = waves_per_block * 2;
    const int grid = (n_nodes + nodes_per_block - 1) / nodes_per_block;
    gemm_st_kernel<<<grid, 256, 0, stream>>>(x, W, a, h, s, t, n_nodes);
  }

  // CSR build
  hist_kernel<<<(E + 255) / 256, 256, 0, stream>>>(src, cnt, E);
  scan_kernel<<<1, 1024, 0, stream>>>(cnt, offs, cursor, n_nodes);
  scatter_kernel<<<(E + 255) / 256, 256, 0, stream>>>(src, dst, cursor,
                                                      dst_sorted, E);

  // Gather-aggregate + normalize (fuses old edge + finalize kernels)
  {
    const int waves_per_block = 4;
    const int grid = (n_nodes + waves_per_block - 1) / waves_per_block;
    aggregate_kernel<<<grid, 256, 0, stream>>>(offs, dst_sorted, h, s, t, out,
                                               n_nodes);
  }
}

// Round 3
// 516.048 us; speedup vs baseline: 1.4772x; 1.4347x over previous
//
#include <hip/hip_runtime.h>
#include <math.h>

#define IN_C 128
#define OUT_C 64
#define ALPHA 0.2f

#define SCAN_BLOCK 256
#define SCAN_ITEMS 4
#define SCAN_TILE (SCAN_BLOCK * SCAN_ITEMS)  // 1024 elements per block

// ---------------------------------------------------------------------------
// Kernel 1: h = x @ W, s = h . a1, t = h . a2
// One wave per 2 nodes; lane c computes h[node][c]. W staged in LDS.
// ---------------------------------------------------------------------------
__global__ __launch_bounds__(256) void gemm_st_kernel(
    const float* __restrict__ x, const float* __restrict__ W,
    const float* __restrict__ a, float* __restrict__ h,
    float* __restrict__ s, float* __restrict__ t, int n_nodes) {
  __shared__ float Ws[IN_C * OUT_C];
  for (int i = threadIdx.x; i < IN_C * OUT_C; i += blockDim.x) Ws[i] = W[i];
  __syncthreads();

  const int wave = threadIdx.x >> 6;
  const int lane = threadIdx.x & 63;
  const int waves_total = gridDim.x * (blockDim.x >> 6);
  const int gwave = blockIdx.x * (blockDim.x >> 6) + wave;

  for (int base = gwave * 2; base < n_nodes; base += waves_total * 2) {
    const int n0 = base;
    const int n1 = base + 1;
    const bool has1 = (n1 < n_nodes);
    const float* x0 = x + (size_t)n0 * IN_C;
    const float* x1 = x + (size_t)(has1 ? n1 : n0) * IN_C;
    float acc0 = 0.f, acc1 = 0.f;
#pragma unroll 8
    for (int k = 0; k < IN_C; ++k) {
      const float wv = Ws[k * OUT_C + lane];
      acc0 += x0[k] * wv;
      acc1 += x1[k] * wv;
    }
    h[(size_t)n0 * OUT_C + lane] = acc0;
    if (has1) h[(size_t)n1 * OUT_C + lane] = acc1;

    const float a1v = a[lane];
    const float a2v = a[OUT_C + lane];
    float sv0 = acc0 * a1v, tv0 = acc0 * a2v;
    float sv1 = acc1 * a1v, tv1 = acc1 * a2v;
#pragma unroll
    for (int off = 32; off; off >>= 1) {
      sv0 += __shfl_down(sv0, off, 64);
      tv0 += __shfl_down(tv0, off, 64);
      sv1 += __shfl_down(sv1, off, 64);
      tv1 += __shfl_down(tv1, off, 64);
    }
    if (lane == 0) {
      s[n0] = sv0;
      t[n0] = tv0;
      if (has1) {
        s[n1] = sv1;
        t[n1] = tv1;
      }
    }
  }
}

// ---------------------------------------------------------------------------
// CSR build: histogram -> 3-pass device-wide scan -> cursor scatter
// ---------------------------------------------------------------------------
__global__ __launch_bounds__(256) void hist_kernel(const int* __restrict__ src,
                                                   int* __restrict__ cnt,
                                                   int E) {
  const int e = blockIdx.x * blockDim.x + threadIdx.x;
  if (e < E) atomicAdd(&cnt[src[e]], 1);
}

// Pass 1: per-block sums (1024 counts per block).
__global__ __launch_bounds__(SCAN_BLOCK) void scan_partial(
    const int* __restrict__ cnt, int* __restrict__ block_sums, int n) {
  const int tid = threadIdx.x;
  const int base = blockIdx.x * SCAN_TILE + tid * SCAN_ITEMS;
  int s = 0;
#pragma unroll
  for (int i = 0; i < SCAN_ITEMS; ++i) {
    const int idx = base + i;
    if (idx < n) s += cnt[idx];
  }
  __shared__ int wsum[SCAN_BLOCK / 64];
#pragma unroll
  for (int off = 32; off; off >>= 1) s += __shfl_down(s, off, 64);
  if ((tid & 63) == 0) wsum[tid >> 6] = s;
  __syncthreads();
  if (tid == 0) {
    int tot = 0;
#pragma unroll
    for (int w = 0; w < SCAN_BLOCK / 64; ++w) tot += wsum[w];
    block_sums[blockIdx.x] = tot;
  }
}

// Pass 2: exclusive scan of block_sums (nb <= 1024) in one block; writes total.
__global__ __launch_bounds__(1024) void scan_blocksums(
    int* __restrict__ block_sums, int nb, int* __restrict__ total_out) {
  __shared__ int sh[1024];
  const int tid = threadIdx.x;
  const int v = (tid < nb) ? block_sums[tid] : 0;
  sh[tid] = v;
  __syncthreads();
  int val = v;
  for (int off = 1; off < 1024; off <<= 1) {
    const int other = (tid >= off) ? sh[tid - off] : 0;
    __syncthreads();
    val += other;
    sh[tid] = val;
    __syncthreads();
  }
  if (tid < nb) block_sums[tid] = val - v;  // exclusive prefix
  if (tid == 1023) *total_out = val;        // grand total -> offs[n]
}

// Pass 3: block-local exclusive scan + block prefix; write offs and cursor.
__global__ __launch_bounds__(SCAN_BLOCK) void scan_final(
    const int* __restrict__ cnt, const int* __restrict__ block_sums,
    int* __restrict__ offs, int* __restrict__ cursor, int n) {
  __shared__ int tsum[SCAN_BLOCK];
  const int tid = threadIdx.x;
  const int base = blockIdx.x * SCAN_TILE + tid * SCAN_ITEMS;
  int local[SCAN_ITEMS];
  int s = 0;
#pragma unroll
  for (int i = 0; i < SCAN_ITEMS; ++i) {
    const int idx = base + i;
    local[i] = (idx < n) ? cnt[idx] : 0;
    s += local[i];
  }
  tsum[tid] = s;
  __syncthreads();
  int val = s;
  for (int off = 1; off < SCAN_BLOCK; off <<= 1) {
    const int other = (tid >= off) ? tsum[tid - off] : 0;
    __syncthreads();
    val += other;
    tsum[tid] = val;
    __syncthreads();
  }
  int prefix = block_sums[blockIdx.x] + (val - s);
#pragma unroll
  for (int i = 0; i < SCAN_ITEMS; ++i) {
    const int idx = base + i;
    if (idx < n) {
      offs[idx] = prefix;
      cursor[idx] = prefix;
      prefix += local[i];
    }
  }
}

__global__ __launch_bounds__(256) void scatter_kernel(
    const int* __restrict__ src, const int* __restrict__ dst,
    int* __restrict__ cursor, int* __restrict__ dst_sorted, int E) {
  const int e = blockIdx.x * blockDim.x + threadIdx.x;
  if (e < E) {
    const int pos = atomicAdd(&cursor[src[e]], 1);
    dst_sorted[pos] = dst[e];
  }
}

// ---------------------------------------------------------------------------
// Aggregate: one wave per node, lane = channel. No atomics.
// ---------------------------------------------------------------------------
__global__ __launch_bounds__(256) void aggregate_kernel(
    const int* __restrict__ offs, const int* __restrict__ dst_sorted,
    const float* __restrict__ h, const float* __restrict__ s,
    const float* __restrict__ t, float* __restrict__ out, int n_nodes) {
  const int lane = threadIdx.x & 63;
  const int gwave = (blockIdx.x * blockDim.x + threadIdx.x) >> 6;
  const int waves_total = (gridDim.x * blockDim.x) >> 6;

  for (int u = gwave; u < n_nodes; u += waves_total) {
    const float su = s[u];
    const int beg = offs[u];
    const int end = offs[u + 1];

    const float z0 = su + t[u];
    const float w0 = expf(z0 > 0.f ? z0 : ALPHA * z0);
    float acc = w0 * h[(size_t)u * OUT_C + lane];
    float denom = w0;

#pragma unroll 4
    for (int j = beg; j < end; ++j) {
      const int v = dst_sorted[j];
      const float z = su + t[v];
      const float w = expf(z > 0.f ? z : ALPHA * z);
      acc += w * h[(size_t)v * OUT_C + lane];
      denom += w;
    }
    out[(size_t)u * OUT_C + lane] = acc / denom;
  }
}

extern "C" void kernel_launch(void* const* d_in, const int* in_sizes, int n_in,
                              void* d_out, int out_size, void* d_ws,
                              size_t ws_size, hipStream_t stream) {
  const float* x = (const float*)d_in[0];
  const float* W = (const float*)d_in[1];
  const float* a = (const float*)d_in[2];
  const int* edge_index = (const int*)d_in[3];

  const int n_nodes = in_sizes[0] / IN_C;
  const int E = in_sizes[3] / 2;
  const int* src = edge_index;
  const int* dst = edge_index + E;

  float* out = (float*)d_out;

  const int n_scan_blocks = (n_nodes + SCAN_TILE - 1) / SCAN_TILE;  // 98

  // Workspace layout (all 4B elements):
  float* h = (float*)d_ws;                         // n_nodes*64
  float* s = h + (size_t)n_nodes * OUT_C;          // n_nodes
  float* t = s + n_nodes;                          // n_nodes
  int* cnt = (int*)(t + n_nodes);                  // n_nodes
  int* offs = cnt + n_nodes;                       // n_nodes+1
  int* cursor = offs + n_nodes + 1;                // n_nodes
  int* block_sums = cursor + n_nodes;              // n_scan_blocks (<=1024)
  int* dst_sorted = block_sums + 1024;             // E

  hipMemsetAsync(cnt, 0, (size_t)n_nodes * sizeof(int), stream);

  // h, s, t (independent of CSR build)
  {
    const int waves_per_block = 4;
    const int nodes_per_block = waves_per_block * 2;
    const int grid = (n_nodes + nodes_per_block - 1) / nodes_per_block;
    gemm_st_kernel<<<grid, 256, 0, stream>>>(x, W, a, h, s, t, n_nodes);
  }

  // CSR build
  hist_kernel<<<(E + 255) / 256, 256, 0, stream>>>(src, cnt, E);
  scan_partial<<<n_scan_blocks, SCAN_BLOCK, 0, stream>>>(cnt, block_sums,
                                                         n_nodes);
  scan_blocksums<<<1, 1024, 0, stream>>>(block_sums, n_scan_blocks,
                                         offs + n_nodes);
  scan_final<<<n_scan_blocks, SCAN_BLOCK, 0, stream>>>(cnt, block_sums, offs,
                                                       cursor, n_nodes);
  scatter_kernel<<<(E + 255) / 256, 256, 0, stream>>>(src, dst, cursor,
                                                      dst_sorted, E);

  // Gather-aggregate + normalize
  {
    const int waves_per_block = 4;
    const int grid = (n_nodes + waves_per_block - 1) / waves_per_block;
    aggregate_kernel<<<grid, 256, 0, stream>>>(offs, dst_sorted, h, s, t, out,
                                               n_nodes);
  }
}

// Round 4
// 408.964 us; speedup vs baseline: 1.8640x; 1.2618x over previous
//
#include <hip/hip_runtime.h>
#include <math.h>

#define IN_C 128
#define OUT_C 64
#define ALPHA 0.2f

#define SCAN_BLOCK 256
#define SCAN_ITEMS 4
#define SCAN_TILE (SCAN_BLOCK * SCAN_ITEMS)  // 1024 elements per block

#define LDK 136  // padded halfwords per LDS row (128 + 8): breaks bank stride

typedef __attribute__((ext_vector_type(8))) short short8;
typedef __attribute__((ext_vector_type(4))) float v4f;

__device__ __forceinline__ ushort f2b(float f) {  // fp32 -> bf16 RNE
  unsigned u = __float_as_uint(f);
  u += 0x7fffu + ((u >> 16) & 1u);
  return (ushort)(u >> 16);
}
__device__ __forceinline__ float b2f(ushort h) {
  return __uint_as_float(((unsigned)h) << 16);
}

// ---------------------------------------------------------------------------
// Kernel 1: h = bf16(x) @ bf16(W) via MFMA 16x16x32, fp32 accumulate.
// Block = 256 threads = 4 waves; block tile = 64 nodes x 64 cols.
// Wave w handles rows [w*16, w*16+16): 4 col-tiles x 4 k-steps = 16 MFMAs.
// s = h.a1, t = h.a2 fused in epilogue (quad-shuffle reduction).
// h stored as bf16 (halves aggregate's gather footprint).
// ---------------------------------------------------------------------------
__global__ __launch_bounds__(256) void gemm_st_kernel(
    const float* __restrict__ x, const float* __restrict__ W,
    const float* __restrict__ a, ushort* __restrict__ hb,
    float* __restrict__ s, float* __restrict__ t, int n_nodes, int n_tiles) {
  __shared__ ushort xs[64 * LDK];
  __shared__ ushort ws[64 * LDK];

  const int tid = threadIdx.x;
  const int wave = tid >> 6;
  const int lane = tid & 63;
  const int li = lane & 15;
  const int quad = lane >> 4;

  // Stage W^T as bf16: ws[n*LDK + k] = bf16(W[k][n]); coalesced global reads.
  for (int i = tid; i < IN_C * OUT_C; i += 256) {
    const int k = i >> 6;
    const int n = i & 63;
    ws[n * LDK + k] = f2b(W[i]);
  }
  __syncthreads();

  // Preload all B fragments (W is shared by every tile).
  // B-frag[ct][kk]: lane holds B[k=kk*32+quad*8+j][n=ct*16+li], j=0..7.
  short8 bfrag[4][4];
#pragma unroll
  for (int ct = 0; ct < 4; ++ct)
#pragma unroll
    for (int kk = 0; kk < 4; ++kk)
      bfrag[ct][kk] =
          *(const short8*)&ws[(ct * 16 + li) * LDK + kk * 32 + quad * 8];

  // Per-lane attention vector values (invariant across tiles).
  float a1v[4], a2v[4];
#pragma unroll
  for (int ct = 0; ct < 4; ++ct) {
    a1v[ct] = a[ct * 16 + li];
    a2v[ct] = a[OUT_C + ct * 16 + li];
  }

  for (int tile = blockIdx.x; tile < n_tiles; tile += gridDim.x) {
    const int row0 = tile * 64;

    __syncthreads();  // previous iteration's xs reads must complete
    // Stage x tile (64 rows x 128) as bf16; float4 coalesced loads.
    for (int i = tid; i < 64 * (IN_C / 4); i += 256) {
      const int r = i >> 5;    // 32 float4 per row
      const int c4 = i & 31;
      int row = row0 + r;
      row = row < n_nodes ? row : n_nodes - 1;
      const float4 v = *(const float4*)&x[(size_t)row * IN_C + c4 * 4];
      uint2 p;
      p.x = (unsigned)f2b(v.x) | ((unsigned)f2b(v.y) << 16);
      p.y = (unsigned)f2b(v.z) | ((unsigned)f2b(v.w) << 16);
      *(uint2*)&xs[r * LDK + c4 * 4] = p;
    }
    __syncthreads();

    v4f acc[4];
#pragma unroll
    for (int ct = 0; ct < 4; ++ct) acc[ct] = (v4f){0.f, 0.f, 0.f, 0.f};

    const int rbase = wave * 16;
#pragma unroll
    for (int kk = 0; kk < 4; ++kk) {
      const short8 af =
          *(const short8*)&xs[(rbase + li) * LDK + kk * 32 + quad * 8];
#pragma unroll
      for (int ct = 0; ct < 4; ++ct)
        acc[ct] = __builtin_amdgcn_mfma_f32_16x16x32_bf16(af, bfrag[ct][kk],
                                                          acc[ct], 0, 0, 0);
    }

    // Epilogue. C/D layout: col = ct*16 + li, row = rbase + quad*4 + r.
    const int growbase = row0 + rbase + quad * 4;
    float ps[4] = {0.f, 0.f, 0.f, 0.f};
    float pt[4] = {0.f, 0.f, 0.f, 0.f};
#pragma unroll
    for (int ct = 0; ct < 4; ++ct) {
#pragma unroll
      for (int r = 0; r < 4; ++r) {
        const float hv = acc[ct][r];
        ps[r] += hv * a1v[ct];
        pt[r] += hv * a2v[ct];
        const int grow = growbase + r;
        if (grow < n_nodes)
          hb[(size_t)grow * OUT_C + ct * 16 + li] = f2b(hv);
      }
    }
    // Reduce ps/pt across the 16 lanes of each quad.
#pragma unroll
    for (int m = 1; m <= 8; m <<= 1) {
#pragma unroll
      for (int r = 0; r < 4; ++r) {
        ps[r] += __shfl_xor(ps[r], m, 64);
        pt[r] += __shfl_xor(pt[r], m, 64);
      }
    }
    if (li < 4) {
      const int grow = growbase + li;
      if (grow < n_nodes) {
        const float sv = li == 0 ? ps[0] : li == 1 ? ps[1] : li == 2 ? ps[2] : ps[3];
        const float tv = li == 0 ? pt[0] : li == 1 ? pt[1] : li == 2 ? pt[2] : pt[3];
        s[grow] = sv;
        t[grow] = tv;
      }
    }
  }
}

// ---------------------------------------------------------------------------
// CSR build: histogram -> 3-pass device-wide scan -> cursor scatter
// ---------------------------------------------------------------------------
__global__ __launch_bounds__(256) void hist_kernel(const int* __restrict__ src,
                                                   int* __restrict__ cnt,
                                                   int E) {
  const int e = blockIdx.x * blockDim.x + threadIdx.x;
  if (e < E) atomicAdd(&cnt[src[e]], 1);
}

__global__ __launch_bounds__(SCAN_BLOCK) void scan_partial(
    const int* __restrict__ cnt, int* __restrict__ block_sums, int n) {
  const int tid = threadIdx.x;
  const int base = blockIdx.x * SCAN_TILE + tid * SCAN_ITEMS;
  int s = 0;
#pragma unroll
  for (int i = 0; i < SCAN_ITEMS; ++i) {
    const int idx = base + i;
    if (idx < n) s += cnt[idx];
  }
  __shared__ int wsum[SCAN_BLOCK / 64];
#pragma unroll
  for (int off = 32; off; off >>= 1) s += __shfl_down(s, off, 64);
  if ((tid & 63) == 0) wsum[tid >> 6] = s;
  __syncthreads();
  if (tid == 0) {
    int tot = 0;
#pragma unroll
    for (int w = 0; w < SCAN_BLOCK / 64; ++w) tot += wsum[w];
    block_sums[blockIdx.x] = tot;
  }
}

__global__ __launch_bounds__(1024) void scan_blocksums(
    int* __restrict__ block_sums, int nb, int* __restrict__ total_out) {
  __shared__ int sh[1024];
  const int tid = threadIdx.x;
  const int v = (tid < nb) ? block_sums[tid] : 0;
  sh[tid] = v;
  __syncthreads();
  int val = v;
  for (int off = 1; off < 1024; off <<= 1) {
    const int other = (tid >= off) ? sh[tid - off] : 0;
    __syncthreads();
    val += other;
    sh[tid] = val;
    __syncthreads();
  }
  if (tid < nb) block_sums[tid] = val - v;
  if (tid == 1023) *total_out = val;
}

__global__ __launch_bounds__(SCAN_BLOCK) void scan_final(
    const int* __restrict__ cnt, const int* __restrict__ block_sums,
    int* __restrict__ offs, int* __restrict__ cursor, int n) {
  __shared__ int tsum[SCAN_BLOCK];
  const int tid = threadIdx.x;
  const int base = blockIdx.x * SCAN_TILE + tid * SCAN_ITEMS;
  int local[SCAN_ITEMS];
  int s = 0;
#pragma unroll
  for (int i = 0; i < SCAN_ITEMS; ++i) {
    const int idx = base + i;
    local[i] = (idx < n) ? cnt[idx] : 0;
    s += local[i];
  }
  tsum[tid] = s;
  __syncthreads();
  int val = s;
  for (int off = 1; off < SCAN_BLOCK; off <<= 1) {
    const int other = (tid >= off) ? tsum[tid - off] : 0;
    __syncthreads();
    val += other;
    tsum[tid] = val;
    __syncthreads();
  }
  int prefix = block_sums[blockIdx.x] + (val - s);
#pragma unroll
  for (int i = 0; i < SCAN_ITEMS; ++i) {
    const int idx = base + i;
    if (idx < n) {
      offs[idx] = prefix;
      cursor[idx] = prefix;
      prefix += local[i];
    }
  }
}

__global__ __launch_bounds__(256) void scatter_kernel(
    const int* __restrict__ src, const int* __restrict__ dst,
    int* __restrict__ cursor, int* __restrict__ dst_sorted, int E) {
  const int e = blockIdx.x * blockDim.x + threadIdx.x;
  if (e < E) {
    const int pos = atomicAdd(&cursor[src[e]], 1);
    dst_sorted[pos] = dst[e];
  }
}

// ---------------------------------------------------------------------------
// Aggregate: one wave per node, lane = channel. Batch-loads up to 64 neighbor
// ids + t-values + exp-weights in parallel, broadcasts via shfl. h is bf16:
// one 128B cache line per gathered row. No atomics.
// ---------------------------------------------------------------------------
__global__ __launch_bounds__(256) void aggregate_kernel(
    const int* __restrict__ offs, const int* __restrict__ dst_sorted,
    const ushort* __restrict__ hb, const float* __restrict__ s,
    const float* __restrict__ t, float* __restrict__ out, int n_nodes) {
  const int lane = threadIdx.x & 63;
  const int gwave = (blockIdx.x * blockDim.x + threadIdx.x) >> 6;
  const int waves_total = (gridDim.x * blockDim.x) >> 6;

  for (int u = gwave; u < n_nodes; u += waves_total) {
    const float su = s[u];
    const int beg = offs[u];
    const int end = offs[u + 1];

    // self-loop
    const float z0 = su + t[u];
    const float w0 = expf(z0 > 0.f ? z0 : ALPHA * z0);
    float acc = w0 * b2f(hb[(size_t)u * OUT_C + lane]);
    float denom = w0;

    for (int b = beg; b < end; b += 64) {
      const int j = b + lane;
      const int idx = j < end ? j : end - 1;
      const int v = dst_sorted[idx];       // parallel gather of ids
      const float tv = t[v];               // parallel gather of t
      const float z = su + tv;
      const float w = expf(z > 0.f ? z : ALPHA * z);  // parallel exp
      const int cnt = min(64, end - b);
      for (int jj = 0; jj < cnt; ++jj) {
        const int vj = __shfl(v, jj, 64);
        const float wj = __shfl(w, jj, 64);
        acc += wj * b2f(hb[(size_t)vj * OUT_C + lane]);
        denom += wj;
      }
    }
    out[(size_t)u * OUT_C + lane] = acc / denom;
  }
}

extern "C" void kernel_launch(void* const* d_in, const int* in_sizes, int n_in,
                              void* d_out, int out_size, void* d_ws,
                              size_t ws_size, hipStream_t stream) {
  const float* x = (const float*)d_in[0];
  const float* W = (const float*)d_in[1];
  const float* a = (const float*)d_in[2];
  const int* edge_index = (const int*)d_in[3];

  const int n_nodes = in_sizes[0] / IN_C;
  const int E = in_sizes[3] / 2;
  const int* src = edge_index;
  const int* dst = edge_index + E;

  float* out = (float*)d_out;

  const int n_scan_blocks = (n_nodes + SCAN_TILE - 1) / SCAN_TILE;

  // Workspace layout (all 4B-aligned):
  ushort* hb = (ushort*)d_ws;                       // n_nodes*64 bf16
  float* s = (float*)(hb + (size_t)n_nodes * OUT_C);// n_nodes
  float* t = s + n_nodes;                           // n_nodes
  int* cnt = (int*)(t + n_nodes);                   // n_nodes
  int* offs = cnt + n_nodes;                        // n_nodes+1
  int* cursor = offs + n_nodes + 1;                 // n_nodes
  int* block_sums = cursor + n_nodes;               // <=1024
  int* dst_sorted = block_sums + 1024;              // E

  hipMemsetAsync(cnt, 0, (size_t)n_nodes * sizeof(int), stream);

  // h (bf16), s, t via MFMA
  {
    const int n_tiles = (n_nodes + 63) / 64;
    gemm_st_kernel<<<n_tiles, 256, 0, stream>>>(x, W, a, hb, s, t, n_nodes,
                                                n_tiles);
  }

  // CSR build
  hist_kernel<<<(E + 255) / 256, 256, 0, stream>>>(src, cnt, E);
  scan_partial<<<n_scan_blocks, SCAN_BLOCK, 0, stream>>>(cnt, block_sums,
                                                         n_nodes);
  scan_blocksums<<<1, 1024, 0, stream>>>(block_sums, n_scan_blocks,
                                         offs + n_nodes);
  scan_final<<<n_scan_blocks, SCAN_BLOCK, 0, stream>>>(cnt, block_sums, offs,
                                                       cursor, n_nodes);
  scatter_kernel<<<(E + 255) / 256, 256, 0, stream>>>(src, dst, cursor,
                                                      dst_sorted, E);

  // Gather-aggregate + normalize
  {
    const int waves_per_block = 4;
    const int grid = (n_nodes + waves_per_block - 1) / waves_per_block;
    aggregate_kernel<<<grid, 256, 0, stream>>>(offs, dst_sorted, hb, s, t, out,
                                               n_nodes);
  }
}

// Round 5
// 385.754 us; speedup vs baseline: 1.9762x; 1.0602x over previous
//
#include <hip/hip_runtime.h>
#include <math.h>

#define IN_C 128
#define OUT_C 64
#define ALPHA 0.2f

#define SCAN_BLOCK 256
#define SCAN_ITEMS 4
#define SCAN_TILE (SCAN_BLOCK * SCAN_ITEMS)  // 1024 elements per block

#define LDK 136  // padded halfwords per LDS row

#define SC_K 8  // edges per thread in hist/scatter (ILP for atomic latency)

typedef __attribute__((ext_vector_type(8))) short short8;
typedef __attribute__((ext_vector_type(4))) float v4f;

__device__ __forceinline__ ushort f2b(float f) {  // fp32 -> bf16 RNE
  unsigned u = __float_as_uint(f);
  u += 0x7fffu + ((u >> 16) & 1u);
  return (ushort)(u >> 16);
}
__device__ __forceinline__ float b2f(ushort h) {
  return __uint_as_float(((unsigned)h) << 16);
}

// ---------------------------------------------------------------------------
// Kernel 1: h = bf16(x) @ bf16(W) via MFMA 16x16x32, fp32 accumulate.
// ---------------------------------------------------------------------------
__global__ __launch_bounds__(256) void gemm_st_kernel(
    const float* __restrict__ x, const float* __restrict__ W,
    const float* __restrict__ a, ushort* __restrict__ hb,
    float* __restrict__ s, float* __restrict__ t, int n_nodes, int n_tiles) {
  __shared__ ushort xs[64 * LDK];
  __shared__ ushort ws[64 * LDK];

  const int tid = threadIdx.x;
  const int wave = tid >> 6;
  const int lane = tid & 63;
  const int li = lane & 15;
  const int quad = lane >> 4;

  for (int i = tid; i < IN_C * OUT_C; i += 256) {
    const int k = i >> 6;
    const int n = i & 63;
    ws[n * LDK + k] = f2b(W[i]);
  }
  __syncthreads();

  short8 bfrag[4][4];
#pragma unroll
  for (int ct = 0; ct < 4; ++ct)
#pragma unroll
    for (int kk = 0; kk < 4; ++kk)
      bfrag[ct][kk] =
          *(const short8*)&ws[(ct * 16 + li) * LDK + kk * 32 + quad * 8];

  float a1v[4], a2v[4];
#pragma unroll
  for (int ct = 0; ct < 4; ++ct) {
    a1v[ct] = a[ct * 16 + li];
    a2v[ct] = a[OUT_C + ct * 16 + li];
  }

  for (int tile = blockIdx.x; tile < n_tiles; tile += gridDim.x) {
    const int row0 = tile * 64;

    __syncthreads();
    for (int i = tid; i < 64 * (IN_C / 4); i += 256) {
      const int r = i >> 5;
      const int c4 = i & 31;
      int row = row0 + r;
      row = row < n_nodes ? row : n_nodes - 1;
      const float4 v = *(const float4*)&x[(size_t)row * IN_C + c4 * 4];
      uint2 p;
      p.x = (unsigned)f2b(v.x) | ((unsigned)f2b(v.y) << 16);
      p.y = (unsigned)f2b(v.z) | ((unsigned)f2b(v.w) << 16);
      *(uint2*)&xs[r * LDK + c4 * 4] = p;
    }
    __syncthreads();

    v4f acc[4];
#pragma unroll
    for (int ct = 0; ct < 4; ++ct) acc[ct] = (v4f){0.f, 0.f, 0.f, 0.f};

    const int rbase = wave * 16;
#pragma unroll
    for (int kk = 0; kk < 4; ++kk) {
      const short8 af =
          *(const short8*)&xs[(rbase + li) * LDK + kk * 32 + quad * 8];
#pragma unroll
      for (int ct = 0; ct < 4; ++ct)
        acc[ct] = __builtin_amdgcn_mfma_f32_16x16x32_bf16(af, bfrag[ct][kk],
                                                          acc[ct], 0, 0, 0);
    }

    const int growbase = row0 + rbase + quad * 4;
    float ps[4] = {0.f, 0.f, 0.f, 0.f};
    float pt[4] = {0.f, 0.f, 0.f, 0.f};
#pragma unroll
    for (int ct = 0; ct < 4; ++ct) {
#pragma unroll
      for (int r = 0; r < 4; ++r) {
        const float hv = acc[ct][r];
        ps[r] += hv * a1v[ct];
        pt[r] += hv * a2v[ct];
        const int grow = growbase + r;
        if (grow < n_nodes)
          hb[(size_t)grow * OUT_C + ct * 16 + li] = f2b(hv);
      }
    }
#pragma unroll
    for (int m = 1; m <= 8; m <<= 1) {
#pragma unroll
      for (int r = 0; r < 4; ++r) {
        ps[r] += __shfl_xor(ps[r], m, 64);
        pt[r] += __shfl_xor(pt[r], m, 64);
      }
    }
    if (li < 4) {
      const int grow = growbase + li;
      if (grow < n_nodes) {
        const float sv = li == 0 ? ps[0] : li == 1 ? ps[1] : li == 2 ? ps[2] : ps[3];
        const float tv = li == 0 ? pt[0] : li == 1 ? pt[1] : li == 2 ? pt[2] : pt[3];
        s[grow] = sv;
        t[grow] = tv;
      }
    }
  }
}

// ---------------------------------------------------------------------------
// CSR build: histogram -> 3-pass scan -> cursor scatter (K-batched for ILP)
// ---------------------------------------------------------------------------
__global__ __launch_bounds__(256) void hist_kernel(const int* __restrict__ src,
                                                   int* __restrict__ cnt,
                                                   int E) {
  const int base = blockIdx.x * (256 * SC_K) + threadIdx.x;
  int vs[SC_K];
  bool valid[SC_K];
#pragma unroll
  for (int i = 0; i < SC_K; ++i) {
    const int e = base + i * 256;
    valid[i] = (e < E);
    vs[i] = src[valid[i] ? e : 0];
  }
#pragma unroll
  for (int i = 0; i < SC_K; ++i)
    if (valid[i]) atomicAdd(&cnt[vs[i]], 1);
}

__global__ __launch_bounds__(SCAN_BLOCK) void scan_partial(
    const int* __restrict__ cnt, int* __restrict__ block_sums, int n) {
  const int tid = threadIdx.x;
  const int base = blockIdx.x * SCAN_TILE + tid * SCAN_ITEMS;
  int s = 0;
#pragma unroll
  for (int i = 0; i < SCAN_ITEMS; ++i) {
    const int idx = base + i;
    if (idx < n) s += cnt[idx];
  }
  __shared__ int wsum[SCAN_BLOCK / 64];
#pragma unroll
  for (int off = 32; off; off >>= 1) s += __shfl_down(s, off, 64);
  if ((tid & 63) == 0) wsum[tid >> 6] = s;
  __syncthreads();
  if (tid == 0) {
    int tot = 0;
#pragma unroll
    for (int w = 0; w < SCAN_BLOCK / 64; ++w) tot += wsum[w];
    block_sums[blockIdx.x] = tot;
  }
}

__global__ __launch_bounds__(1024) void scan_blocksums(
    int* __restrict__ block_sums, int nb, int* __restrict__ total_out) {
  __shared__ int sh[1024];
  const int tid = threadIdx.x;
  const int v = (tid < nb) ? block_sums[tid] : 0;
  sh[tid] = v;
  __syncthreads();
  int val = v;
  for (int off = 1; off < 1024; off <<= 1) {
    const int other = (tid >= off) ? sh[tid - off] : 0;
    __syncthreads();
    val += other;
    sh[tid] = val;
    __syncthreads();
  }
  if (tid < nb) block_sums[tid] = val - v;
  if (tid == 1023) *total_out = val;
}

__global__ __launch_bounds__(SCAN_BLOCK) void scan_final(
    const int* __restrict__ cnt, const int* __restrict__ block_sums,
    int* __restrict__ offs, int* __restrict__ cursor, int n) {
  __shared__ int tsum[SCAN_BLOCK];
  const int tid = threadIdx.x;
  const int base = blockIdx.x * SCAN_TILE + tid * SCAN_ITEMS;
  int local[SCAN_ITEMS];
  int s = 0;
#pragma unroll
  for (int i = 0; i < SCAN_ITEMS; ++i) {
    const int idx = base + i;
    local[i] = (idx < n) ? cnt[idx] : 0;
    s += local[i];
  }
  tsum[tid] = s;
  __syncthreads();
  int val = s;
  for (int off = 1; off < SCAN_BLOCK; off <<= 1) {
    const int other = (tid >= off) ? tsum[tid - off] : 0;
    __syncthreads();
    val += other;
    tsum[tid] = val;
    __syncthreads();
  }
  int prefix = block_sums[blockIdx.x] + (val - s);
#pragma unroll
  for (int i = 0; i < SCAN_ITEMS; ++i) {
    const int idx = base + i;
    if (idx < n) {
      offs[idx] = prefix;
      cursor[idx] = prefix;
      prefix += local[i];
    }
  }
}

// K-batched scatter: 8 independent value-returning atomics in flight per
// thread instead of 1 -> 8x latency overlap on the atomic round-trip.
__global__ __launch_bounds__(256) void scatter_kernel(
    const int* __restrict__ src, const int* __restrict__ dst,
    int* __restrict__ cursor, int* __restrict__ dst_sorted, int E) {
  const int base = blockIdx.x * (256 * SC_K) + threadIdx.x;
  int vs[SC_K], vd[SC_K], pos[SC_K];
  bool valid[SC_K];
#pragma unroll
  for (int i = 0; i < SC_K; ++i) {
    const int e = base + i * 256;
    valid[i] = (e < E);
    const int ee = valid[i] ? e : 0;
    vs[i] = src[ee];
    vd[i] = dst[ee];
  }
#pragma unroll
  for (int i = 0; i < SC_K; ++i)
    if (valid[i]) pos[i] = atomicAdd(&cursor[vs[i]], 1);
#pragma unroll
  for (int i = 0; i < SC_K; ++i)
    if (valid[i]) dst_sorted[pos[i]] = vd[i];
}

// ---------------------------------------------------------------------------
// Aggregate: one wave per node, lane = channel. No atomics.
// ---------------------------------------------------------------------------
__global__ __launch_bounds__(256) void aggregate_kernel(
    const int* __restrict__ offs, const int* __restrict__ dst_sorted,
    const ushort* __restrict__ hb, const float* __restrict__ s,
    const float* __restrict__ t, float* __restrict__ out, int n_nodes) {
  const int lane = threadIdx.x & 63;
  const int gwave = (blockIdx.x * blockDim.x + threadIdx.x) >> 6;
  const int waves_total = (gridDim.x * blockDim.x) >> 6;

  for (int u = gwave; u < n_nodes; u += waves_total) {
    const float su = s[u];
    const int beg = offs[u];
    const int end = offs[u + 1];

    const float z0 = su + t[u];
    const float w0 = expf(z0 > 0.f ? z0 : ALPHA * z0);
    float acc = w0 * b2f(hb[(size_t)u * OUT_C + lane]);
    float denom = w0;

    for (int b = beg; b < end; b += 64) {
      const int j = b + lane;
      const int idx = j < end ? j : end - 1;
      const int v = dst_sorted[idx];
      const float tv = t[v];
      const float z = su + tv;
      const float w = expf(z > 0.f ? z : ALPHA * z);
      const int cnt = min(64, end - b);
      for (int jj = 0; jj < cnt; ++jj) {
        const int vj = __shfl(v, jj, 64);
        const float wj = __shfl(w, jj, 64);
        acc += wj * b2f(hb[(size_t)vj * OUT_C + lane]);
        denom += wj;
      }
    }
    out[(size_t)u * OUT_C + lane] = acc / denom;
  }
}

extern "C" void kernel_launch(void* const* d_in, const int* in_sizes, int n_in,
                              void* d_out, int out_size, void* d_ws,
                              size_t ws_size, hipStream_t stream) {
  const float* x = (const float*)d_in[0];
  const float* W = (const float*)d_in[1];
  const float* a = (const float*)d_in[2];
  const int* edge_index = (const int*)d_in[3];

  const int n_nodes = in_sizes[0] / IN_C;
  const int E = in_sizes[3] / 2;
  const int* src = edge_index;
  const int* dst = edge_index + E;

  float* out = (float*)d_out;

  const int n_scan_blocks = (n_nodes + SCAN_TILE - 1) / SCAN_TILE;

  ushort* hb = (ushort*)d_ws;                        // n_nodes*64 bf16
  float* s = (float*)(hb + (size_t)n_nodes * OUT_C); // n_nodes
  float* t = s + n_nodes;                            // n_nodes
  int* cnt = (int*)(t + n_nodes);                    // n_nodes
  int* offs = cnt + n_nodes;                         // n_nodes+1
  int* cursor = offs + n_nodes + 1;                  // n_nodes
  int* block_sums = cursor + n_nodes;                // <=1024
  int* dst_sorted = block_sums + 1024;               // E

  hipMemsetAsync(cnt, 0, (size_t)n_nodes * sizeof(int), stream);

  {
    const int n_tiles = (n_nodes + 63) / 64;
    gemm_st_kernel<<<n_tiles, 256, 0, stream>>>(x, W, a, hb, s, t, n_nodes,
                                                n_tiles);
  }

  const int ebatch_grid = (E + 256 * SC_K - 1) / (256 * SC_K);
  hist_kernel<<<ebatch_grid, 256, 0, stream>>>(src, cnt, E);
  scan_partial<<<n_scan_blocks, SCAN_BLOCK, 0, stream>>>(cnt, block_sums,
                                                         n_nodes);
  scan_blocksums<<<1, 1024, 0, stream>>>(block_sums, n_scan_blocks,
                                         offs + n_nodes);
  scan_final<<<n_scan_blocks, SCAN_BLOCK, 0, stream>>>(cnt, block_sums, offs,
                                                       cursor, n_nodes);
  scatter_kernel<<<ebatch_grid, 256, 0, stream>>>(src, dst, cursor, dst_sorted,
                                                  E);

  {
    const int waves_per_block = 4;
    const int grid = (n_nodes + waves_per_block - 1) / waves_per_block;
    aggregate_kernel<<<grid, 256, 0, stream>>>(offs, dst_sorted, hb, s, t, out,
                                               n_nodes);
  }
}

// Round 6
// 324.576 us; speedup vs baseline: 2.3486x; 1.1885x over previous
//
#include <hip/hip_runtime.h>
#include <math.h>

#define IN_C 128
#define OUT_C 64
#define ALPHA 0.2f

#define SCAN_BLOCK 256
#define SCAN_ITEMS 4
#define SCAN_TILE (SCAN_BLOCK * SCAN_ITEMS)  // 1024 elements per block

#define LDK 136  // padded halfwords per LDS row

#define SC_K 8  // edges per thread in hist/scatter (ILP for atomic latency)

typedef __attribute__((ext_vector_type(8))) short short8;
typedef __attribute__((ext_vector_type(4))) float v4f;

__device__ __forceinline__ ushort f2b(float f) {  // fp32 -> bf16 RNE
  unsigned u = __float_as_uint(f);
  u += 0x7fffu + ((u >> 16) & 1u);
  return (ushort)(u >> 16);
}
__device__ __forceinline__ float b2f(ushort h) {
  return __uint_as_float(((unsigned)h) << 16);
}

// ---------------------------------------------------------------------------
// Kernel 1: h = bf16(x) @ bf16(W) via MFMA 16x16x32, fp32 accumulate.
// ---------------------------------------------------------------------------
__global__ __launch_bounds__(256) void gemm_st_kernel(
    const float* __restrict__ x, const float* __restrict__ W,
    const float* __restrict__ a, ushort* __restrict__ hb,
    float* __restrict__ s, float* __restrict__ t, int n_nodes, int n_tiles) {
  __shared__ ushort xs[64 * LDK];
  __shared__ ushort ws[64 * LDK];

  const int tid = threadIdx.x;
  const int wave = tid >> 6;
  const int lane = tid & 63;
  const int li = lane & 15;
  const int quad = lane >> 4;

  for (int i = tid; i < IN_C * OUT_C; i += 256) {
    const int k = i >> 6;
    const int n = i & 63;
    ws[n * LDK + k] = f2b(W[i]);
  }
  __syncthreads();

  short8 bfrag[4][4];
#pragma unroll
  for (int ct = 0; ct < 4; ++ct)
#pragma unroll
    for (int kk = 0; kk < 4; ++kk)
      bfrag[ct][kk] =
          *(const short8*)&ws[(ct * 16 + li) * LDK + kk * 32 + quad * 8];

  float a1v[4], a2v[4];
#pragma unroll
  for (int ct = 0; ct < 4; ++ct) {
    a1v[ct] = a[ct * 16 + li];
    a2v[ct] = a[OUT_C + ct * 16 + li];
  }

  for (int tile = blockIdx.x; tile < n_tiles; tile += gridDim.x) {
    const int row0 = tile * 64;

    __syncthreads();
    for (int i = tid; i < 64 * (IN_C / 4); i += 256) {
      const int r = i >> 5;
      const int c4 = i & 31;
      int row = row0 + r;
      row = row < n_nodes ? row : n_nodes - 1;
      const float4 v = *(const float4*)&x[(size_t)row * IN_C + c4 * 4];
      uint2 p;
      p.x = (unsigned)f2b(v.x) | ((unsigned)f2b(v.y) << 16);
      p.y = (unsigned)f2b(v.z) | ((unsigned)f2b(v.w) << 16);
      *(uint2*)&xs[r * LDK + c4 * 4] = p;
    }
    __syncthreads();

    v4f acc[4];
#pragma unroll
    for (int ct = 0; ct < 4; ++ct) acc[ct] = (v4f){0.f, 0.f, 0.f, 0.f};

    const int rbase = wave * 16;
#pragma unroll
    for (int kk = 0; kk < 4; ++kk) {
      const short8 af =
          *(const short8*)&xs[(rbase + li) * LDK + kk * 32 + quad * 8];
#pragma unroll
      for (int ct = 0; ct < 4; ++ct)
        acc[ct] = __builtin_amdgcn_mfma_f32_16x16x32_bf16(af, bfrag[ct][kk],
                                                          acc[ct], 0, 0, 0);
    }

    const int growbase = row0 + rbase + quad * 4;
    float ps[4] = {0.f, 0.f, 0.f, 0.f};
    float pt[4] = {0.f, 0.f, 0.f, 0.f};
#pragma unroll
    for (int ct = 0; ct < 4; ++ct) {
#pragma unroll
      for (int r = 0; r < 4; ++r) {
        const float hv = acc[ct][r];
        ps[r] += hv * a1v[ct];
        pt[r] += hv * a2v[ct];
        const int grow = growbase + r;
        if (grow < n_nodes)
          hb[(size_t)grow * OUT_C + ct * 16 + li] = f2b(hv);
      }
    }
#pragma unroll
    for (int m = 1; m <= 8; m <<= 1) {
#pragma unroll
      for (int r = 0; r < 4; ++r) {
        ps[r] += __shfl_xor(ps[r], m, 64);
        pt[r] += __shfl_xor(pt[r], m, 64);
      }
    }
    if (li < 4) {
      const int grow = growbase + li;
      if (grow < n_nodes) {
        const float sv = li == 0 ? ps[0] : li == 1 ? ps[1] : li == 2 ? ps[2] : ps[3];
        const float tv = li == 0 ? pt[0] : li == 1 ? pt[1] : li == 2 ? pt[2] : pt[3];
        s[grow] = sv;
        t[grow] = tv;
      }
    }
  }
}

// ---------------------------------------------------------------------------
// CSR build: histogram -> 3-pass scan -> cursor scatter (K-batched for ILP)
// ---------------------------------------------------------------------------
__global__ __launch_bounds__(256) void hist_kernel(const int* __restrict__ src,
                                                   int* __restrict__ cnt,
                                                   int E) {
  const int base = blockIdx.x * (256 * SC_K) + threadIdx.x;
  int vs[SC_K];
  bool valid[SC_K];
#pragma unroll
  for (int i = 0; i < SC_K; ++i) {
    const int e = base + i * 256;
    valid[i] = (e < E);
    vs[i] = src[valid[i] ? e : 0];
  }
#pragma unroll
  for (int i = 0; i < SC_K; ++i)
    if (valid[i]) atomicAdd(&cnt[vs[i]], 1);
}

__global__ __launch_bounds__(SCAN_BLOCK) void scan_partial(
    const int* __restrict__ cnt, int* __restrict__ block_sums, int n) {
  const int tid = threadIdx.x;
  const int base = blockIdx.x * SCAN_TILE + tid * SCAN_ITEMS;
  int s = 0;
#pragma unroll
  for (int i = 0; i < SCAN_ITEMS; ++i) {
    const int idx = base + i;
    if (idx < n) s += cnt[idx];
  }
  __shared__ int wsum[SCAN_BLOCK / 64];
#pragma unroll
  for (int off = 32; off; off >>= 1) s += __shfl_down(s, off, 64);
  if ((tid & 63) == 0) wsum[tid >> 6] = s;
  __syncthreads();
  if (tid == 0) {
    int tot = 0;
#pragma unroll
    for (int w = 0; w < SCAN_BLOCK / 64; ++w) tot += wsum[w];
    block_sums[blockIdx.x] = tot;
  }
}

__global__ __launch_bounds__(1024) void scan_blocksums(
    int* __restrict__ block_sums, int nb, int* __restrict__ total_out) {
  __shared__ int sh[1024];
  const int tid = threadIdx.x;
  const int v = (tid < nb) ? block_sums[tid] : 0;
  sh[tid] = v;
  __syncthreads();
  int val = v;
  for (int off = 1; off < 1024; off <<= 1) {
    const int other = (tid >= off) ? sh[tid - off] : 0;
    __syncthreads();
    val += other;
    sh[tid] = val;
    __syncthreads();
  }
  if (tid < nb) block_sums[tid] = val - v;
  if (tid == 1023) *total_out = val;
}

__global__ __launch_bounds__(SCAN_BLOCK) void scan_final(
    const int* __restrict__ cnt, const int* __restrict__ block_sums,
    int* __restrict__ offs, int* __restrict__ cursor, int n) {
  __shared__ int tsum[SCAN_BLOCK];
  const int tid = threadIdx.x;
  const int base = blockIdx.x * SCAN_TILE + tid * SCAN_ITEMS;
  int local[SCAN_ITEMS];
  int s = 0;
#pragma unroll
  for (int i = 0; i < SCAN_ITEMS; ++i) {
    const int idx = base + i;
    local[i] = (idx < n) ? cnt[idx] : 0;
    s += local[i];
  }
  tsum[tid] = s;
  __syncthreads();
  int val = s;
  for (int off = 1; off < SCAN_BLOCK; off <<= 1) {
    const int other = (tid >= off) ? tsum[tid - off] : 0;
    __syncthreads();
    val += other;
    tsum[tid] = val;
    __syncthreads();
  }
  int prefix = block_sums[blockIdx.x] + (val - s);
#pragma unroll
  for (int i = 0; i < SCAN_ITEMS; ++i) {
    const int idx = base + i;
    if (idx < n) {
      offs[idx] = prefix;
      cursor[idx] = prefix;
      prefix += local[i];
    }
  }
}

__global__ __launch_bounds__(256) void scatter_kernel(
    const int* __restrict__ src, const int* __restrict__ dst,
    int* __restrict__ cursor, int* __restrict__ dst_sorted, int E) {
  const int base = blockIdx.x * (256 * SC_K) + threadIdx.x;
  int vs[SC_K], vd[SC_K], pos[SC_K];
  bool valid[SC_K];
#pragma unroll
  for (int i = 0; i < SC_K; ++i) {
    const int e = base + i * 256;
    valid[i] = (e < E);
    const int ee = valid[i] ? e : 0;
    vs[i] = src[ee];
    vd[i] = dst[ee];
  }
#pragma unroll
  for (int i = 0; i < SC_K; ++i)
    if (valid[i]) pos[i] = atomicAdd(&cursor[vs[i]], 1);
#pragma unroll
  for (int i = 0; i < SC_K; ++i)
    if (valid[i]) dst_sorted[pos[i]] = vd[i];
}

// ---------------------------------------------------------------------------
// Aggregate: one wave per node; each HALF-wave (32 lanes x uint = 128B)
// gathers one neighbor row; 8 edges per inner iteration -> 4 independent
// loads in flight per wave. Halves merged by shfl_xor(32) at the end.
// ---------------------------------------------------------------------------
__global__ __launch_bounds__(256) void aggregate_kernel(
    const int* __restrict__ offs, const int* __restrict__ dst_sorted,
    const uint* __restrict__ hbp, const float* __restrict__ s,
    const float* __restrict__ t, float* __restrict__ out, int n_nodes) {
  const int lane = threadIdx.x & 63;
  const int ch2 = lane & 31;   // channel-pair index
  const int half = lane >> 5;  // which half-wave
  const int gwave = (blockIdx.x * blockDim.x + threadIdx.x) >> 6;
  const int waves_total = (gridDim.x * blockDim.x) >> 6;

  for (int u = gwave; u < n_nodes; u += waves_total) {
    const float su = s[u];
    const int beg = offs[u];
    const int end = offs[u + 1];

    float acc0 = 0.f, acc1 = 0.f, denom = 0.f;
    if (half == 0) {  // self-loop counted once (half 0 only)
      const float z0 = su + t[u];
      const float w0 = expf(z0 > 0.f ? z0 : ALPHA * z0);
      const uint p = hbp[(size_t)u * 32 + ch2];
      acc0 = w0 * b2f((ushort)(p & 0xffffu));
      acc1 = w0 * b2f((ushort)(p >> 16));
      denom = w0;
    }

    for (int b = beg; b < end; b += 64) {
      const int cnt = min(64, end - b);
      // Batch stage: lane j holds edge b+j's neighbor id and exp-weight.
      const int j = b + lane;
      const int idx = j < end ? j : end - 1;
      const int v = dst_sorted[idx];
      const float tv = t[v];
      const float z = su + tv;
      const float w = expf(z > 0.f ? z : ALPHA * z);

      for (int jj = 0; jj < cnt; jj += 8) {
        // This half-wave's 4 edges: jj+half, jj+2+half, jj+4+half, jj+6+half
        int vj[4];
        float wj[4];
#pragma unroll
        for (int q = 0; q < 4; ++q) {
          const int mj = jj + 2 * q + half;
          const int sl = mj < cnt ? mj : cnt - 1;
          vj[q] = __shfl(v, sl, 64);
          const float ww = __shfl(w, sl, 64);
          wj[q] = mj < cnt ? ww : 0.f;
        }
        uint p[4];
#pragma unroll
        for (int q = 0; q < 4; ++q) p[q] = hbp[(size_t)vj[q] * 32 + ch2];
#pragma unroll
        for (int q = 0; q < 4; ++q) {
          acc0 += wj[q] * b2f((ushort)(p[q] & 0xffffu));
          acc1 += wj[q] * b2f((ushort)(p[q] >> 16));
          denom += wj[q];
        }
      }
    }
    acc0 += __shfl_xor(acc0, 32, 64);
    acc1 += __shfl_xor(acc1, 32, 64);
    denom += __shfl_xor(denom, 32, 64);
    if (half == 0) {
      float2 o;
      o.x = acc0 / denom;
      o.y = acc1 / denom;
      *(float2*)&out[(size_t)u * OUT_C + ch2 * 2] = o;
    }
  }
}

extern "C" void kernel_launch(void* const* d_in, const int* in_sizes, int n_in,
                              void* d_out, int out_size, void* d_ws,
                              size_t ws_size, hipStream_t stream) {
  const float* x = (const float*)d_in[0];
  const float* W = (const float*)d_in[1];
  const float* a = (const float*)d_in[2];
  const int* edge_index = (const int*)d_in[3];

  const int n_nodes = in_sizes[0] / IN_C;
  const int E = in_sizes[3] / 2;
  const int* src = edge_index;
  const int* dst = edge_index + E;

  float* out = (float*)d_out;

  const int n_scan_blocks = (n_nodes + SCAN_TILE - 1) / SCAN_TILE;

  ushort* hb = (ushort*)d_ws;                        // n_nodes*64 bf16
  float* s = (float*)(hb + (size_t)n_nodes * OUT_C); // n_nodes
  float* t = s + n_nodes;                            // n_nodes
  int* cnt = (int*)(t + n_nodes);                    // n_nodes
  int* offs = cnt + n_nodes;                         // n_nodes+1
  int* cursor = offs + n_nodes + 1;                  // n_nodes
  int* block_sums = cursor + n_nodes;                // <=1024
  int* dst_sorted = block_sums + 1024;               // E

  hipMemsetAsync(cnt, 0, (size_t)n_nodes * sizeof(int), stream);

  {
    const int n_tiles = (n_nodes + 63) / 64;
    gemm_st_kernel<<<n_tiles, 256, 0, stream>>>(x, W, a, hb, s, t, n_nodes,
                                                n_tiles);
  }

  const int ebatch_grid = (E + 256 * SC_K - 1) / (256 * SC_K);
  hist_kernel<<<ebatch_grid, 256, 0, stream>>>(src, cnt, E);
  scan_partial<<<n_scan_blocks, SCAN_BLOCK, 0, stream>>>(cnt, block_sums,
                                                         n_nodes);
  scan_blocksums<<<1, 1024, 0, stream>>>(block_sums, n_scan_blocks,
                                         offs + n_nodes);
  scan_final<<<n_scan_blocks, SCAN_BLOCK, 0, stream>>>(cnt, block_sums, offs,
                                                       cursor, n_nodes);
  scatter_kernel<<<ebatch_grid, 256, 0, stream>>>(src, dst, cursor, dst_sorted,
                                                  E);

  {
    const int waves_per_block = 4;
    const int grid = (n_nodes + waves_per_block - 1) / waves_per_block;
    aggregate_kernel<<<grid, 256, 0, stream>>>(offs, dst_sorted, (const uint*)hb,
                                               s, t, out, n_nodes);
  }
}